// Round 4
// baseline (191.388 us; speedup 1.0000x reference)
//
#include <hip/hip_runtime.h>

#define B_ 32
#define N_ 4096
#define D_ 64
#define C_ 129
#define BC_ 4
#define QROWS_ 17   // q-rows per attn block: 8 groups/b * 32 b = 256 blocks
#define NBLK_ 256

// Device-scope grid barrier with state in ws, zeroed per-iteration by a
// hipMemsetAsync graph node in kernel_launch (this is the fix for round-3:
// cg::grid_group barrier state does not reset across graph replays).
// Arrival: device-scope RELEASE fetch_add (cross-XCD coherent).
// Spin: RELAXED + s_sleep backoff; ACQUIRE load on exit invalidates L1/L2.
__device__ __forceinline__ void gbar(int* bar, int idx) {
    __syncthreads();  // compiler emits vmcnt(0) drain: block's stores are in L2
    if (threadIdx.x == 0) {
        __hip_atomic_fetch_add(&bar[idx], 1, __ATOMIC_RELEASE, __HIP_MEMORY_SCOPE_AGENT);
        int spins = 0;
        while (__hip_atomic_load(&bar[idx], __ATOMIC_RELAXED, __HIP_MEMORY_SCOPE_AGENT) < NBLK_) {
            __builtin_amdgcn_s_sleep(32);
            if (++spins > (1 << 21)) break;   // failsafe: wrong-answer beats hang
        }
        (void)__hip_atomic_load(&bar[idx], __ATOMIC_ACQUIRE, __HIP_MEMORY_SCOPE_AGENT);
    }
    __syncthreads();
}

// One kernel, 256 blocks x 256 threads, 1 block/CU (80.7 KB LDS), all resident.
//   A: counting sort (blocks 0..3)        -> gbar(0)
//   B: fused Q/K/V segment sums           -> gbar(1)
//   C: attention over centers + DIRECT scatter of output rows via sidx
//      (replaces the old gather stage: no vout, no 3rd barrier)
__global__ __launch_bounds__(256) void k_fused(const float* __restrict__ q,
                                               const float* __restrict__ k,
                                               const float* __restrict__ v,
                                               const int* __restrict__ cl,
                                               float* __restrict__ counts,
                                               int* __restrict__ offsets,
                                               int* __restrict__ sidx,
                                               float* __restrict__ sums,
                                               int* __restrict__ bar,
                                               float* __restrict__ out,
                                               float* __restrict__ aout) {
    __shared__ float4 kc4[C_ * 17];       // K centers (16 data float4 + 1 pad)
    __shared__ float4 vc4[C_ * 17];       // V centers
    __shared__ float cnt_s[C_];
    __shared__ float arow[4][4][132];     // per-wave A rows
    __shared__ int scnt[C_];
    __shared__ int sbase[C_];
    __shared__ int scur[C_];

    int tid = threadIdx.x;
    int bid = blockIdx.x;
    int wave = tid >> 6, lane = tid & 63;

    // ================================================== stage A: counting sort
    if (bid < BC_) {
        int bc = bid;
        for (int i = tid; i < C_; i += 256) { scnt[i] = 0; scur[i] = 0; }
        __syncthreads();
        const int4* g4 = (const int4*)(cl + bc * N_);
        for (int n = tid; n < N_ / 4; n += 256) {
            int4 c4 = g4[n];
            atomicAdd(&scnt[c4.x], 1);
            atomicAdd(&scnt[c4.y], 1);
            atomicAdd(&scnt[c4.z], 1);
            atomicAdd(&scnt[c4.w], 1);
        }
        __syncthreads();
        if (tid < C_) {
            int acc = 0;
            for (int i = 0; i < tid; i++) acc += scnt[i];
            sbase[tid] = acc;
        }
        __syncthreads();
        for (int i = tid; i < C_; i += 256) {
            counts[bc * C_ + i] = (float)scnt[i];
            offsets[bc * (C_ + 1) + i] = sbase[i];
        }
        if (tid == 0) offsets[bc * (C_ + 1) + C_] = N_;
        for (int n = tid; n < N_ / 4; n += 256) {
            int4 c4 = g4[n];
            int n0 = n * 4;
            sidx[bc * N_ + sbase[c4.x] + atomicAdd(&scur[c4.x], 1)] = n0;
            sidx[bc * N_ + sbase[c4.y] + atomicAdd(&scur[c4.y], 1)] = n0 + 1;
            sidx[bc * N_ + sbase[c4.z] + atomicAdd(&scur[c4.z], 1)] = n0 + 2;
            sidx[bc * N_ + sbase[c4.w] + atomicAdd(&scur[c4.w], 1)] = n0 + 3;
        }
    }
    gbar(bar, 0);

    // ================================================== stage B: segment sums
    // 4128 (b,c) tasks over 1024 waves; body identical to the verified k_segsum4.
    {
        int sub = lane >> 4, d4 = lane & 15;
        for (int t = bid * 4 + wave; t < B_ * C_; t += 1024) {
            int b = t / C_;
            int c = t - b * C_;
            int bc = b & 3;
            int start = offsets[bc * (C_ + 1) + c];
            int end = offsets[bc * (C_ + 1) + c + 1];
            int cnt = end - start;

            const float4* q4 = (const float4*)(q + (size_t)b * N_ * D_);
            const float4* k4 = (const float4*)(k + (size_t)b * N_ * D_);
            const float4* v4 = (const float4*)(v + (size_t)b * N_ * D_);
            const int* si = sidx + bc * N_;

            float4 aq = make_float4(0.f, 0.f, 0.f, 0.f);
            float4 ak = make_float4(0.f, 0.f, 0.f, 0.f);
            float4 av = make_float4(0.f, 0.f, 0.f, 0.f);

            if (cnt > 0) {
                int last = end - 1;
                int ia = start + sub, ib = ia + 4, ic = ia + 8, id = ia + 12;
                int ra = si[min(ia, last)], rb = si[min(ib, last)];
                int rc = si[min(ic, last)], rd = si[min(id, last)];
                for (int i0 = start; i0 < end; i0 += 16) {
                    int ca = ia, cb = ib, cc = ic, cd = id;
                    int ua = ra, ub = rb, uc = rc, ud = rd;
                    ia += 16; ib += 16; ic += 16; id += 16;
                    if (i0 + 16 < end) {
                        ra = si[min(ia, last)]; rb = si[min(ib, last)];
                        rc = si[min(ic, last)]; rd = si[min(id, last)];
                    }
                    float ma = (ca < end) ? 1.f : 0.f;
                    float mb = (cb < end) ? 1.f : 0.f;
                    float mc = (cc < end) ? 1.f : 0.f;
                    float md = (cd < end) ? 1.f : 0.f;
                    float4 qa = q4[ua * 16 + d4], qb = q4[ub * 16 + d4];
                    float4 qc = q4[uc * 16 + d4], qd = q4[ud * 16 + d4];
                    float4 ka = k4[ua * 16 + d4], kb = k4[ub * 16 + d4];
                    float4 kc = k4[uc * 16 + d4], kd = k4[ud * 16 + d4];
                    float4 va = v4[ua * 16 + d4], vb = v4[ub * 16 + d4];
                    float4 vc = v4[uc * 16 + d4], vd = v4[ud * 16 + d4];
                    aq.x += ma * qa.x + mb * qb.x + mc * qc.x + md * qd.x;
                    aq.y += ma * qa.y + mb * qb.y + mc * qc.y + md * qd.y;
                    aq.z += ma * qa.z + mb * qb.z + mc * qc.z + md * qd.z;
                    aq.w += ma * qa.w + mb * qb.w + mc * qc.w + md * qd.w;
                    ak.x += ma * ka.x + mb * kb.x + mc * kc.x + md * kd.x;
                    ak.y += ma * ka.y + mb * kb.y + mc * kc.y + md * kd.y;
                    ak.z += ma * ka.z + mb * kb.z + mc * kc.z + md * kd.z;
                    ak.w += ma * ka.w + mb * kb.w + mc * kc.w + md * kd.w;
                    av.x += ma * va.x + mb * vb.x + mc * vc.x + md * vd.x;
                    av.y += ma * va.y + mb * vb.y + mc * vc.y + md * vd.y;
                    av.z += ma * va.z + mb * vb.z + mc * vc.z + md * vd.z;
                    av.w += ma * va.w + mb * vb.w + mc * vc.w + md * vd.w;
                }
            }
#pragma unroll
            for (int off = 16; off <= 32; off <<= 1) {
                aq.x += __shfl_xor(aq.x, off, 64); aq.y += __shfl_xor(aq.y, off, 64);
                aq.z += __shfl_xor(aq.z, off, 64); aq.w += __shfl_xor(aq.w, off, 64);
                ak.x += __shfl_xor(ak.x, off, 64); ak.y += __shfl_xor(ak.y, off, 64);
                ak.z += __shfl_xor(ak.z, off, 64); ak.w += __shfl_xor(ak.w, off, 64);
                av.x += __shfl_xor(av.x, off, 64); av.y += __shfl_xor(av.y, off, 64);
                av.z += __shfl_xor(av.z, off, 64); av.w += __shfl_xor(av.w, off, 64);
            }
            if (sub == 0) {
                float w = (cnt > 0) ? 1.f / (float)cnt : 0.f;
                float4 oq = make_float4(aq.x * w, aq.y * w, aq.z * w, aq.w * w);
                float4 ok = make_float4(ak.x * w, ak.y * w, ak.z * w, ak.w * w);
                float4 ov = make_float4(av.x * w, av.y * w, av.z * w, av.w * w);
                ((float4*)(sums + (size_t)b * C_ * D_))[c * 16 + d4] = oq;
                ((float4*)(sums + ((size_t)B_ + b) * C_ * D_))[c * 16 + d4] = ok;
                ((float4*)(sums + ((size_t)2 * B_ + b) * C_ * D_))[c * 16 + d4] = ov;
            }
        }
    }
    gbar(bar, 1);

    // ================================================== stage C: attention + scatter
    {
        int b = bid >> 3;
        int qg = bid & 7;
        int q0 = qg * QROWS_;
        int qcnt = min(QROWS_, C_ - q0);
        int bc = b & 3;

        for (int i = tid; i < C_; i += 256)
            cnt_s[i] = counts[bc * C_ + i];

        const float4* qsum4 = (const float4*)(sums + (size_t)b * C_ * D_);
        const float4* ksum4 = (const float4*)(sums + ((size_t)B_ + b) * C_ * D_);
        const float4* vsum4 = (const float4*)(sums + ((size_t)2 * B_ + b) * C_ * D_);

        for (int i = tid; i < C_ * 16; i += 256) {
            int c = i >> 4, d4 = i & 15;
            kc4[c * 17 + d4] = ksum4[i];
            vc4[c * 17 + d4] = vsum4[i];
        }
        __syncthreads();

        const int* si = sidx + bc * N_;
        float4* ob = (float4*)(out + (size_t)b * N_ * D_);

        int wv = __builtin_amdgcn_readfirstlane(wave);

        for (int tt = wv; tt * 4 < qcnt; tt += 4) {
            int t4 = tt * 4;
            const float4* qp0 = qsum4 + (size_t)(q0 + min(t4 + 0, qcnt - 1)) * 16;
            const float4* qp1 = qsum4 + (size_t)(q0 + min(t4 + 1, qcnt - 1)) * 16;
            const float4* qp2 = qsum4 + (size_t)(q0 + min(t4 + 2, qcnt - 1)) * 16;
            const float4* qp3 = qsum4 + (size_t)(q0 + min(t4 + 3, qcnt - 1)) * 16;
            float s0[4] = {0, 0, 0, 0}, s1[4] = {0, 0, 0, 0}, s2[4] = {0, 0, 0, 0};
#pragma unroll 4
            for (int d4 = 0; d4 < 16; d4++) {
                float4 kv0 = kc4[lane * 17 + d4];
                float4 kv1 = kc4[(lane + 64) * 17 + d4];
                float4 kv2 = kc4[128 * 17 + d4];
                float4 qv0 = qp0[d4], qv1 = qp1[d4], qv2 = qp2[d4], qv3 = qp3[d4];
                s0[0] += qv0.x * kv0.x + qv0.y * kv0.y + qv0.z * kv0.z + qv0.w * kv0.w;
                s1[0] += qv0.x * kv1.x + qv0.y * kv1.y + qv0.z * kv1.z + qv0.w * kv1.w;
                s2[0] += qv0.x * kv2.x + qv0.y * kv2.y + qv0.z * kv2.z + qv0.w * kv2.w;
                s0[1] += qv1.x * kv0.x + qv1.y * kv0.y + qv1.z * kv0.z + qv1.w * kv0.w;
                s1[1] += qv1.x * kv1.x + qv1.y * kv1.y + qv1.z * kv1.z + qv1.w * kv1.w;
                s2[1] += qv1.x * kv2.x + qv1.y * kv2.y + qv1.z * kv2.z + qv1.w * kv2.w;
                s0[2] += qv2.x * kv0.x + qv2.y * kv0.y + qv2.z * kv0.z + qv2.w * kv0.w;
                s1[2] += qv2.x * kv1.x + qv2.y * kv1.y + qv2.z * kv1.z + qv2.w * kv1.w;
                s2[2] += qv2.x * kv2.x + qv2.y * kv2.y + qv2.z * kv2.z + qv2.w * kv2.w;
                s0[3] += qv3.x * kv0.x + qv3.y * kv0.y + qv3.z * kv0.z + qv3.w * kv0.w;
                s1[3] += qv3.x * kv1.x + qv3.y * kv1.y + qv3.z * kv1.z + qv3.w * kv1.w;
                s2[3] += qv3.x * kv2.x + qv3.y * kv2.y + qv3.z * kv2.z + qv3.w * kv2.w;
            }
#pragma unroll
            for (int r = 0; r < 4; r++) {
                if (t4 + r >= qcnt) break;
                int qrow = q0 + t4 + r;
                float m = fmaxf(s0[r], s1[r]);
                if (lane == 0) m = fmaxf(m, s2[r]);
                for (int off = 32; off > 0; off >>= 1)
                    m = fmaxf(m, __shfl_xor(m, off, 64));
                float e0 = __expf(s0[r] - m) * cnt_s[lane];
                float e1 = __expf(s1[r] - m) * cnt_s[lane + 64];
                float e2 = (lane == 0) ? __expf(s2[r] - m) * cnt_s[128] : 0.f;
                float sum = e0 + e1 + e2;
                for (int off = 32; off > 0; off >>= 1)
                    sum += __shfl_xor(sum, off, 64);
                float inv = 1.f / sum;
                float a0 = e0 * inv, a1 = e1 * inv;
                arow[wave][r][lane] = a0;
                arow[wave][r][64 + lane] = a1;
                if (lane == 0) {
                    arow[wave][r][128] = e2 * inv;
                    aout[b * C_ + qrow] = a0;   // A_full[:, :, 0]
                }
            }
            __builtin_amdgcn_s_waitcnt(0);       // arow writes visible in-wave
            __builtin_amdgcn_sched_barrier(0);   // don't hoist ds_reads above
            int rr = lane >> 4, d4 = lane & 15;
            const float4* ar4 = (const float4*)arow[wave][rr];
            float4 o = make_float4(0.f, 0.f, 0.f, 0.f);
            for (int k4 = 0; k4 < 32; k4++) {
                float4 a4 = ar4[k4];
                float4 v0 = vc4[(k4 * 4 + 0) * 17 + d4];
                float4 v1 = vc4[(k4 * 4 + 1) * 17 + d4];
                float4 v2 = vc4[(k4 * 4 + 2) * 17 + d4];
                float4 v3 = vc4[(k4 * 4 + 3) * 17 + d4];
                o.x += a4.x * v0.x + a4.y * v1.x + a4.z * v2.x + a4.w * v3.x;
                o.y += a4.x * v0.y + a4.y * v1.y + a4.z * v2.y + a4.w * v3.y;
                o.z += a4.x * v0.z + a4.y * v1.z + a4.z * v2.z + a4.w * v3.z;
                o.w += a4.x * v0.w + a4.y * v1.w + a4.z * v2.w + a4.w * v3.w;
            }
            {
                float a128 = arow[wave][rr][128];
                float4 vv = vc4[128 * 17 + d4];
                o.x += a128 * vv.x; o.y += a128 * vv.y;
                o.z += a128 * vv.z; o.w += a128 * vv.w;
            }
            // ---- direct scatter: broadcast o to every member row of this cluster
            if (t4 + rr < qcnt) {
                int qrow = q0 + t4 + rr;
                int s = offsets[bc * (C_ + 1) + qrow];
                int e = offsets[bc * (C_ + 1) + qrow + 1];
                for (int mm = s; mm < e; mm++) {
                    int n = si[mm];              // broadcast load (same addr, 16 lanes)
                    ob[n * 16 + d4] = o;         // 16 lanes -> contiguous 256B row
                }
            }
        }
    }
}

// ---------------------------------------------------------------- launch
extern "C" void kernel_launch(void* const* d_in, const int* in_sizes, int n_in,
                              void* d_out, int out_size, void* d_ws, size_t ws_size,
                              hipStream_t stream) {
    const float* q = (const float*)d_in[0];
    const float* k = (const float*)d_in[1];
    const float* v = (const float*)d_in[2];
    const int* cl = (const int*)d_in[3];
    float* out = (float*)d_out;
    float* aout = out + (size_t)B_ * N_ * D_;   // A_full[:, :, 0] tail

    float* ws = (float*)d_ws;
    float* counts = ws;                                   // [4][C_] (pad to 1024)
    float* sums = ws + 1024;                              // [3][B_][C_][D_] pre-scaled centers
    int* bar = (int*)(sums + (size_t)3 * B_ * C_ * D_);   // [64] grid-barrier counters
    int* offsets = bar + 64;                              // [4][C_+1]
    int* sidx = offsets + 4 * (C_ + 1);                   // [4][N_]

    // Reset barrier state EVERY graph replay (this node is captured in the graph).
    hipMemsetAsync(bar, 0, 64 * sizeof(int), stream);
    k_fused<<<NBLK_, 256, 0, stream>>>(q, k, v, cl, counts, offsets, sidx,
                                       sums, bar, out, aout);
}

// Round 5
// 171.032 us; speedup vs baseline: 1.1190x; 1.1190x over previous
//
#include <hip/hip_runtime.h>

#define B_ 32
#define N_ 4096
#define D_ 64
#define C_ 129
#define BC_ 4
#define CG_ 33   // ceil(C_/4): 4 waves/block = 4 clusters/block
#define QROWS_ 17  // q-rows per attn block: 8 blocks/b, exactly 256 blocks total

// ---------------------------------------------------------------- counting sort
// One block per cluster-batch row, 1024 threads. Produces counts (float),
// offsets [C_+1], and sidx: row indices sorted by cluster.
__global__ __launch_bounds__(1024) void k_sort(const int* __restrict__ cl,
                                               float* __restrict__ counts,
                                               int* __restrict__ offsets,
                                               int* __restrict__ sidx) {
    __shared__ int cnt[C_];
    __shared__ int base[C_];
    __shared__ int cur[C_];
    int bc = blockIdx.x, tid = threadIdx.x;
    for (int i = tid; i < C_; i += 1024) { cnt[i] = 0; cur[i] = 0; }
    __syncthreads();
    const int4* g4 = (const int4*)(cl + bc * N_);
    for (int n = tid; n < N_ / 4; n += 1024) {
        int4 c4 = g4[n];
        atomicAdd(&cnt[c4.x], 1);
        atomicAdd(&cnt[c4.y], 1);
        atomicAdd(&cnt[c4.z], 1);
        atomicAdd(&cnt[c4.w], 1);
    }
    __syncthreads();
    if (tid < C_) {
        int acc = 0;
        for (int i = 0; i < tid; i++) acc += cnt[i];
        base[tid] = acc;
    }
    __syncthreads();
    for (int i = tid; i < C_; i += 1024) {
        counts[bc * C_ + i] = (float)cnt[i];
        offsets[bc * (C_ + 1) + i] = base[i];
    }
    if (tid == 0) offsets[bc * (C_ + 1) + C_] = N_;
    for (int n = tid; n < N_ / 4; n += 1024) {
        int4 c4 = g4[n];
        int n0 = n * 4;
        sidx[bc * N_ + base[c4.x] + atomicAdd(&cur[c4.x], 1)] = n0;
        sidx[bc * N_ + base[c4.y] + atomicAdd(&cur[c4.y], 1)] = n0 + 1;
        sidx[bc * N_ + base[c4.z] + atomicAdd(&cur[c4.z], 1)] = n0 + 2;
        sidx[bc * N_ + base[c4.w] + atomicAdd(&cur[c4.w], 1)] = n0 + 3;
    }
}

// ---------------------------------------------------------------- fused segment sums
// One wave per (b, cluster); Q, K, V together: 12 independent 1KB row-gathers
// in flight per iteration. Index loads for iteration i+1 issued before
// iteration i's data is consumed. Centers written once, pre-scaled by 1/count.
// Runs in its own kernel (zero LDS) at ~16 waves/CU — round-4 showed fusing
// this stage under the attn kernel's 80KB LDS (4 waves/CU) costs ~2x.
__global__ __launch_bounds__(256) void k_segsum4(const float* __restrict__ q,
                                                 const float* __restrict__ k,
                                                 const float* __restrict__ v,
                                                 const int* __restrict__ offsets,
                                                 const int* __restrict__ sidx,
                                                 float* __restrict__ sums) {
    int bid = blockIdx.x;
    int cg = bid % CG_;
    int b = bid / CG_;
    int wave = threadIdx.x >> 6, lane = threadIdx.x & 63;
    int c = cg * 4 + wave;
    if (c >= C_) return;
    int bc = b & 3;
    int start = offsets[bc * (C_ + 1) + c];
    int end = offsets[bc * (C_ + 1) + c + 1];
    int cnt = end - start;
    int sub = lane >> 4, d4 = lane & 15;

    const float4* q4 = (const float4*)(q + (size_t)b * N_ * D_);
    const float4* k4 = (const float4*)(k + (size_t)b * N_ * D_);
    const float4* v4 = (const float4*)(v + (size_t)b * N_ * D_);
    const int* si = sidx + bc * N_;

    float4 aq = make_float4(0.f, 0.f, 0.f, 0.f);
    float4 ak = make_float4(0.f, 0.f, 0.f, 0.f);
    float4 av = make_float4(0.f, 0.f, 0.f, 0.f);

    if (cnt > 0) {
        int last = end - 1;
        int ia = start + sub, ib = ia + 4, ic = ia + 8, id = ia + 12;
        int ra = si[min(ia, last)], rb = si[min(ib, last)];
        int rc = si[min(ic, last)], rd = si[min(id, last)];
        for (int i0 = start; i0 < end; i0 += 16) {
            int ca = ia, cb = ib, cc = ic, cd = id;
            int ua = ra, ub = rb, uc = rc, ud = rd;
            ia += 16; ib += 16; ic += 16; id += 16;
            if (i0 + 16 < end) {
                ra = si[min(ia, last)]; rb = si[min(ib, last)];
                rc = si[min(ic, last)]; rd = si[min(id, last)];
            }
            float ma = (ca < end) ? 1.f : 0.f;
            float mb = (cb < end) ? 1.f : 0.f;
            float mc = (cc < end) ? 1.f : 0.f;
            float md = (cd < end) ? 1.f : 0.f;
            float4 qa = q4[ua * 16 + d4], qb = q4[ub * 16 + d4];
            float4 qc = q4[uc * 16 + d4], qd = q4[ud * 16 + d4];
            float4 ka = k4[ua * 16 + d4], kb = k4[ub * 16 + d4];
            float4 kc = k4[uc * 16 + d4], kd = k4[ud * 16 + d4];
            float4 va = v4[ua * 16 + d4], vb = v4[ub * 16 + d4];
            float4 vc = v4[uc * 16 + d4], vd = v4[ud * 16 + d4];
            aq.x += ma * qa.x + mb * qb.x + mc * qc.x + md * qd.x;
            aq.y += ma * qa.y + mb * qb.y + mc * qc.y + md * qd.y;
            aq.z += ma * qa.z + mb * qb.z + mc * qc.z + md * qd.z;
            aq.w += ma * qa.w + mb * qb.w + mc * qc.w + md * qd.w;
            ak.x += ma * ka.x + mb * kb.x + mc * kc.x + md * kd.x;
            ak.y += ma * ka.y + mb * kb.y + mc * kc.y + md * kd.y;
            ak.z += ma * ka.z + mb * kb.z + mc * kc.z + md * kd.z;
            ak.w += ma * ka.w + mb * kb.w + mc * kc.w + md * kd.w;
            av.x += ma * va.x + mb * vb.x + mc * vc.x + md * vd.x;
            av.y += ma * va.y + mb * vb.y + mc * vc.y + md * vd.y;
            av.z += ma * va.z + mb * vb.z + mc * vc.z + md * vd.z;
            av.w += ma * va.w + mb * vb.w + mc * vc.w + md * vd.w;
        }
    }
#pragma unroll
    for (int off = 16; off <= 32; off <<= 1) {
        aq.x += __shfl_xor(aq.x, off, 64); aq.y += __shfl_xor(aq.y, off, 64);
        aq.z += __shfl_xor(aq.z, off, 64); aq.w += __shfl_xor(aq.w, off, 64);
        ak.x += __shfl_xor(ak.x, off, 64); ak.y += __shfl_xor(ak.y, off, 64);
        ak.z += __shfl_xor(ak.z, off, 64); ak.w += __shfl_xor(ak.w, off, 64);
        av.x += __shfl_xor(av.x, off, 64); av.y += __shfl_xor(av.y, off, 64);
        av.z += __shfl_xor(av.z, off, 64); av.w += __shfl_xor(av.w, off, 64);
    }
    if (sub == 0) {
        float w = (cnt > 0) ? 1.f / (float)cnt : 0.f;
        float4 oq = make_float4(aq.x * w, aq.y * w, aq.z * w, aq.w * w);
        float4 ok = make_float4(ak.x * w, ak.y * w, ak.z * w, ak.w * w);
        float4 ov = make_float4(av.x * w, av.y * w, av.z * w, av.w * w);
        ((float4*)(sums + (size_t)b * C_ * D_))[c * 16 + d4] = oq;
        ((float4*)(sums + ((size_t)B_ + b) * C_ * D_))[c * 16 + d4] = ok;
        ((float4*)(sums + ((size_t)2 * B_ + b) * C_ * D_))[c * 16 + d4] = ov;
    }
}

// ---------------------------------------------------------------- attention + scatter
// grid: B * 8 blocks (17 q-rows per block -> exactly 256 blocks, one scheduling
// round; LDS 79.1 KB -> 2 blocks/CU). K,V centers in LDS (PV from global was
// the round-1 59us regression). Q-row reads are wave-uniform broadcasts from
// global. Output rows are scattered DIRECTLY via sidx (round-4 verified),
// which eliminates the separate gather kernel and the vout round-trip.
__global__ __launch_bounds__(256, 2) void k_attn_sc(const float* __restrict__ sums,
                                                    const float* __restrict__ counts,
                                                    const int* __restrict__ offsets,
                                                    const int* __restrict__ sidx,
                                                    float* __restrict__ out,
                                                    float* __restrict__ aout) {
    __shared__ float4 kc4[C_ * 17];       // K centers, 16 data float4 + 1 pad
    __shared__ float4 vc4[C_ * 17];       // V centers
    __shared__ float cnt_s[C_];
    __shared__ float arow[4][4][132];     // per-wave A rows (k=0..128, pad to 132)

    int b = blockIdx.x >> 3;
    int qg = blockIdx.x & 7;
    int q0 = qg * QROWS_;
    int qcnt = min(QROWS_, C_ - q0);
    int tid = threadIdx.x;
    int bc = b & 3;

    for (int i = tid; i < C_; i += 256)
        cnt_s[i] = counts[bc * C_ + i];

    const float4* qsum4 = (const float4*)(sums + (size_t)b * C_ * D_);
    const float4* ksum4 = (const float4*)(sums + ((size_t)B_ + b) * C_ * D_);
    const float4* vsum4 = (const float4*)(sums + ((size_t)2 * B_ + b) * C_ * D_);

    for (int i = tid; i < C_ * 16; i += 256) {
        int c = i >> 4, d4 = i & 15;
        kc4[c * 17 + d4] = ksum4[i];
        vc4[c * 17 + d4] = vsum4[i];
    }
    __syncthreads();

    const int* si = sidx + bc * N_;
    float4* ob = (float4*)(out + (size_t)b * N_ * D_);

    int wave = __builtin_amdgcn_readfirstlane(tid >> 6);
    int lane = tid & 63;

    for (int tt = wave; tt * 4 < qcnt; tt += 4) {
        int t4 = tt * 4;
        // per-tile Q row pointers (wave-uniform; clamped for the tail)
        const float4* qp0 = qsum4 + (size_t)(q0 + min(t4 + 0, qcnt - 1)) * 16;
        const float4* qp1 = qsum4 + (size_t)(q0 + min(t4 + 1, qcnt - 1)) * 16;
        const float4* qp2 = qsum4 + (size_t)(q0 + min(t4 + 2, qcnt - 1)) * 16;
        const float4* qp3 = qsum4 + (size_t)(q0 + min(t4 + 3, qcnt - 1)) * 16;
        // ---- QK: 4 q-rows x (k=lane, k=lane+64, k=128)
        float s0[4] = {0, 0, 0, 0}, s1[4] = {0, 0, 0, 0}, s2[4] = {0, 0, 0, 0};
#pragma unroll 4
        for (int d4 = 0; d4 < 16; d4++) {
            float4 kv0 = kc4[lane * 17 + d4];
            float4 kv1 = kc4[(lane + 64) * 17 + d4];
            float4 kv2 = kc4[128 * 17 + d4];
            float4 qv0 = qp0[d4], qv1 = qp1[d4], qv2 = qp2[d4], qv3 = qp3[d4];
            s0[0] += qv0.x * kv0.x + qv0.y * kv0.y + qv0.z * kv0.z + qv0.w * kv0.w;
            s1[0] += qv0.x * kv1.x + qv0.y * kv1.y + qv0.z * kv1.z + qv0.w * kv1.w;
            s2[0] += qv0.x * kv2.x + qv0.y * kv2.y + qv0.z * kv2.z + qv0.w * kv2.w;
            s0[1] += qv1.x * kv0.x + qv1.y * kv0.y + qv1.z * kv0.z + qv1.w * kv0.w;
            s1[1] += qv1.x * kv1.x + qv1.y * kv1.y + qv1.z * kv1.z + qv1.w * kv1.w;
            s2[1] += qv1.x * kv2.x + qv1.y * kv2.y + qv1.z * kv2.z + qv1.w * kv2.w;
            s0[2] += qv2.x * kv0.x + qv2.y * kv0.y + qv2.z * kv0.z + qv2.w * kv0.w;
            s1[2] += qv2.x * kv1.x + qv2.y * kv1.y + qv2.z * kv1.z + qv2.w * kv1.w;
            s2[2] += qv2.x * kv2.x + qv2.y * kv2.y + qv2.z * kv2.z + qv2.w * kv2.w;
            s0[3] += qv3.x * kv0.x + qv3.y * kv0.y + qv3.z * kv0.z + qv3.w * kv0.w;
            s1[3] += qv3.x * kv1.x + qv3.y * kv1.y + qv3.z * kv1.z + qv3.w * kv1.w;
            s2[3] += qv3.x * kv2.x + qv3.y * kv2.y + qv3.z * kv2.z + qv3.w * kv2.w;
        }
        // ---- softmax (weighted by counts, renormalized)
#pragma unroll
        for (int r = 0; r < 4; r++) {
            if (t4 + r >= qcnt) break;
            int qrow = q0 + t4 + r;
            float m = fmaxf(s0[r], s1[r]);
            if (lane == 0) m = fmaxf(m, s2[r]);
            for (int off = 32; off > 0; off >>= 1)
                m = fmaxf(m, __shfl_xor(m, off, 64));
            float e0 = __expf(s0[r] - m) * cnt_s[lane];
            float e1 = __expf(s1[r] - m) * cnt_s[lane + 64];
            float e2 = (lane == 0) ? __expf(s2[r] - m) * cnt_s[128] : 0.f;
            float sum = e0 + e1 + e2;
            for (int off = 32; off > 0; off >>= 1)
                sum += __shfl_xor(sum, off, 64);
            float inv = 1.f / sum;
            float a0 = e0 * inv, a1 = e1 * inv;
            arow[wave][r][lane] = a0;
            arow[wave][r][64 + lane] = a1;
            if (lane == 0) {
                arow[wave][r][128] = e2 * inv;
                aout[b * C_ + qrow] = a0;   // A_full[:, :, 0]
            }
        }
        __builtin_amdgcn_s_waitcnt(0);       // arow writes visible in-wave
        __builtin_amdgcn_sched_barrier(0);   // don't let ds_reads hoist above
        // ---- V product: lane = (row within tile, d4)
        int rr = lane >> 4, d4 = lane & 15;
        const float4* ar4 = (const float4*)arow[wave][rr];
        float4 o = make_float4(0.f, 0.f, 0.f, 0.f);
        for (int k4 = 0; k4 < 32; k4++) {
            float4 a4 = ar4[k4];
            float4 v0 = vc4[(k4 * 4 + 0) * 17 + d4];
            float4 v1 = vc4[(k4 * 4 + 1) * 17 + d4];
            float4 v2 = vc4[(k4 * 4 + 2) * 17 + d4];
            float4 v3 = vc4[(k4 * 4 + 3) * 17 + d4];
            o.x += a4.x * v0.x + a4.y * v1.x + a4.z * v2.x + a4.w * v3.x;
            o.y += a4.x * v0.y + a4.y * v1.y + a4.z * v2.y + a4.w * v3.y;
            o.z += a4.x * v0.z + a4.y * v1.z + a4.z * v2.z + a4.w * v3.z;
            o.w += a4.x * v0.w + a4.y * v1.w + a4.z * v2.w + a4.w * v3.w;
        }
        {
            float a128 = arow[wave][rr][128];
            float4 vv = vc4[128 * 17 + d4];
            o.x += a128 * vv.x; o.y += a128 * vv.y;
            o.z += a128 * vv.z; o.w += a128 * vv.w;
        }
        // ---- direct scatter: broadcast o to every member row of this cluster
        if (t4 + rr < qcnt) {
            int qrow = q0 + t4 + rr;
            int s = offsets[bc * (C_ + 1) + qrow];
            int e = offsets[bc * (C_ + 1) + qrow + 1];
            for (int mm = s; mm < e; mm++) {
                int n = si[mm];              // broadcast load (same addr, 16 lanes)
                ob[n * 16 + d4] = o;         // 16 lanes -> contiguous 256B row
            }
        }
    }
}

// ---------------------------------------------------------------- launch
extern "C" void kernel_launch(void* const* d_in, const int* in_sizes, int n_in,
                              void* d_out, int out_size, void* d_ws, size_t ws_size,
                              hipStream_t stream) {
    const float* q = (const float*)d_in[0];
    const float* k = (const float*)d_in[1];
    const float* v = (const float*)d_in[2];
    const int* cl = (const int*)d_in[3];
    float* out = (float*)d_out;
    float* aout = out + (size_t)B_ * N_ * D_;   // A_full[:, :, 0] tail

    float* ws = (float*)d_ws;
    float* counts = ws;                                   // [4][C_] (pad to 1024)
    float* sums = ws + 1024;                              // [3][B_][C_][D_] pre-scaled centers
    int* offsets = (int*)(sums + (size_t)3 * B_ * C_ * D_); // [4][C_+1]
    int* sidx = offsets + 4 * (C_ + 1);                   // [4][N_]

    k_sort<<<BC_, 1024, 0, stream>>>(cl, counts, offsets, sidx);
    k_segsum4<<<B_ * CG_, 256, 0, stream>>>(q, k, v, offsets, sidx, sums);
    k_attn_sc<<<B_ * 8, 256, 0, stream>>>(sums, counts, offsets, sidx, out, aout);
}

// Round 6
// 164.695 us; speedup vs baseline: 1.1621x; 1.0385x over previous
//
#include <hip/hip_runtime.h>

#define B_ 32
#define N_ 4096
#define D_ 64
#define C_ 129
#define BC_ 4
#define CG_ 33   // ceil(C_/4): 4 waves/block = 4 clusters/block
#define QROWS_ 8   // q-rows per attn block: 17 groups/b * 32 b = 544 blocks (2/CU co-resident)

// ---------------------------------------------------------------- counting sort
__global__ __launch_bounds__(1024) void k_sort(const int* __restrict__ cl,
                                               float* __restrict__ counts,
                                               int* __restrict__ offsets,
                                               int* __restrict__ sidx) {
    __shared__ int cnt[C_];
    __shared__ int base[C_];
    __shared__ int cur[C_];
    int bc = blockIdx.x, tid = threadIdx.x;
    for (int i = tid; i < C_; i += 1024) { cnt[i] = 0; cur[i] = 0; }
    __syncthreads();
    const int4* g4 = (const int4*)(cl + bc * N_);
    for (int n = tid; n < N_ / 4; n += 1024) {
        int4 c4 = g4[n];
        atomicAdd(&cnt[c4.x], 1);
        atomicAdd(&cnt[c4.y], 1);
        atomicAdd(&cnt[c4.z], 1);
        atomicAdd(&cnt[c4.w], 1);
    }
    __syncthreads();
    if (tid < C_) {
        int acc = 0;
        for (int i = 0; i < tid; i++) acc += cnt[i];
        base[tid] = acc;
    }
    __syncthreads();
    for (int i = tid; i < C_; i += 1024) {
        counts[bc * C_ + i] = (float)cnt[i];
        offsets[bc * (C_ + 1) + i] = base[i];
    }
    if (tid == 0) offsets[bc * (C_ + 1) + C_] = N_;
    for (int n = tid; n < N_ / 4; n += 1024) {
        int4 c4 = g4[n];
        int n0 = n * 4;
        sidx[bc * N_ + base[c4.x] + atomicAdd(&cur[c4.x], 1)] = n0;
        sidx[bc * N_ + base[c4.y] + atomicAdd(&cur[c4.y], 1)] = n0 + 1;
        sidx[bc * N_ + base[c4.z] + atomicAdd(&cur[c4.z], 1)] = n0 + 2;
        sidx[bc * N_ + base[c4.w] + atomicAdd(&cur[c4.w], 1)] = n0 + 3;
    }
}

// ---------------------------------------------------------------- fused segment sums
// One wave per (b, cluster); zero LDS -> high occupancy (r4 showed fusing this
// under an 80KB-LDS kernel costs ~2x). Verified body, unchanged since r0.
__global__ __launch_bounds__(256) void k_segsum4(const float* __restrict__ q,
                                                 const float* __restrict__ k,
                                                 const float* __restrict__ v,
                                                 const int* __restrict__ offsets,
                                                 const int* __restrict__ sidx,
                                                 float* __restrict__ sums) {
    int bid = blockIdx.x;
    int cg = bid % CG_;
    int b = bid / CG_;
    int wave = threadIdx.x >> 6, lane = threadIdx.x & 63;
    int c = cg * 4 + wave;
    if (c >= C_) return;
    int bc = b & 3;
    int start = offsets[bc * (C_ + 1) + c];
    int end = offsets[bc * (C_ + 1) + c + 1];
    int cnt = end - start;
    int sub = lane >> 4, d4 = lane & 15;

    const float4* q4 = (const float4*)(q + (size_t)b * N_ * D_);
    const float4* k4 = (const float4*)(k + (size_t)b * N_ * D_);
    const float4* v4 = (const float4*)(v + (size_t)b * N_ * D_);
    const int* si = sidx + bc * N_;

    float4 aq = make_float4(0.f, 0.f, 0.f, 0.f);
    float4 ak = make_float4(0.f, 0.f, 0.f, 0.f);
    float4 av = make_float4(0.f, 0.f, 0.f, 0.f);

    if (cnt > 0) {
        int last = end - 1;
        int ia = start + sub, ib = ia + 4, ic = ia + 8, id = ia + 12;
        int ra = si[min(ia, last)], rb = si[min(ib, last)];
        int rc = si[min(ic, last)], rd = si[min(id, last)];
        for (int i0 = start; i0 < end; i0 += 16) {
            int ca = ia, cb = ib, cc = ic, cd = id;
            int ua = ra, ub = rb, uc = rc, ud = rd;
            ia += 16; ib += 16; ic += 16; id += 16;
            if (i0 + 16 < end) {
                ra = si[min(ia, last)]; rb = si[min(ib, last)];
                rc = si[min(ic, last)]; rd = si[min(id, last)];
            }
            float ma = (ca < end) ? 1.f : 0.f;
            float mb = (cb < end) ? 1.f : 0.f;
            float mc = (cc < end) ? 1.f : 0.f;
            float md = (cd < end) ? 1.f : 0.f;
            float4 qa = q4[ua * 16 + d4], qb = q4[ub * 16 + d4];
            float4 qc = q4[uc * 16 + d4], qd = q4[ud * 16 + d4];
            float4 ka = k4[ua * 16 + d4], kb = k4[ub * 16 + d4];
            float4 kc = k4[uc * 16 + d4], kd = k4[ud * 16 + d4];
            float4 va = v4[ua * 16 + d4], vb = v4[ub * 16 + d4];
            float4 vc = v4[uc * 16 + d4], vd = v4[ud * 16 + d4];
            aq.x += ma * qa.x + mb * qb.x + mc * qc.x + md * qd.x;
            aq.y += ma * qa.y + mb * qb.y + mc * qc.y + md * qd.y;
            aq.z += ma * qa.z + mb * qb.z + mc * qc.z + md * qd.z;
            aq.w += ma * qa.w + mb * qb.w + mc * qc.w + md * qd.w;
            ak.x += ma * ka.x + mb * kb.x + mc * kc.x + md * kd.x;
            ak.y += ma * ka.y + mb * kb.y + mc * kc.y + md * kd.y;
            ak.z += ma * ka.z + mb * kb.z + mc * kc.z + md * kd.z;
            ak.w += ma * ka.w + mb * kb.w + mc * kc.w + md * kd.w;
            av.x += ma * va.x + mb * vb.x + mc * vc.x + md * vd.x;
            av.y += ma * va.y + mb * vb.y + mc * vc.y + md * vd.y;
            av.z += ma * va.z + mb * vb.z + mc * vc.z + md * vd.z;
            av.w += ma * va.w + mb * vb.w + mc * vc.w + md * vd.w;
        }
    }
#pragma unroll
    for (int off = 16; off <= 32; off <<= 1) {
        aq.x += __shfl_xor(aq.x, off, 64); aq.y += __shfl_xor(aq.y, off, 64);
        aq.z += __shfl_xor(aq.z, off, 64); aq.w += __shfl_xor(aq.w, off, 64);
        ak.x += __shfl_xor(ak.x, off, 64); ak.y += __shfl_xor(ak.y, off, 64);
        ak.z += __shfl_xor(ak.z, off, 64); ak.w += __shfl_xor(ak.w, off, 64);
        av.x += __shfl_xor(av.x, off, 64); av.y += __shfl_xor(av.y, off, 64);
        av.z += __shfl_xor(av.z, off, 64); av.w += __shfl_xor(av.w, off, 64);
    }
    if (sub == 0) {
        float w = (cnt > 0) ? 1.f / (float)cnt : 0.f;
        float4 oq = make_float4(aq.x * w, aq.y * w, aq.z * w, aq.w * w);
        float4 ok = make_float4(ak.x * w, ak.y * w, ak.z * w, ak.w * w);
        float4 ov = make_float4(av.x * w, av.y * w, av.z * w, av.w * w);
        ((float4*)(sums + (size_t)b * C_ * D_))[c * 16 + d4] = oq;
        ((float4*)(sums + ((size_t)B_ + b) * C_ * D_))[c * 16 + d4] = ok;
        ((float4*)(sums + ((size_t)2 * B_ + b) * C_ * D_))[c * 16 + d4] = ov;
    }
}

// ---------------------------------------------------------------- attention + scatter
// grid: 544 blocks = 17 q-groups x 32 b. LDS ~74.9 KB -> 2 blocks TRULY
// co-resident per CU (r0-r5 all ran 1 block/CU: a 256-block grid never uses
// the 2-block capacity). bid = qg*32 + b so all 17 blocks of batch b hit the
// same XCD (bid % 8 == b % 8) -> b's sums rows stay in one L2.
// Per wave: 2-row tile. PV lanes: rr=lane>>5 (row), half=(lane>>4)&1 (k-half),
// d4=lane&15; halves combined via shfl_xor(16); scatter split between halves.
__global__ __launch_bounds__(256, 2) void k_attn_sc(const float* __restrict__ sums,
                                                    const float* __restrict__ counts,
                                                    const int* __restrict__ offsets,
                                                    const int* __restrict__ sidx,
                                                    float* __restrict__ out,
                                                    float* __restrict__ aout) {
    __shared__ float4 kc4[C_ * 17];       // K centers, 16 data float4 + 1 pad
    __shared__ float4 vc4[C_ * 17];       // V centers
    __shared__ float cnt_s[C_];
    __shared__ float arow[4][2][132];     // per-wave A rows (2-row tiles)

    int bid = blockIdx.x;
    int b = bid & 31;          // XCD-locality: blocks of batch b are == b (mod 32)
    int qg = bid >> 5;         // 0..16
    int q0 = qg * QROWS_;
    int qcnt = min(QROWS_, C_ - q0);
    int tid = threadIdx.x;
    int bc = b & 3;

    for (int i = tid; i < C_; i += 256)
        cnt_s[i] = counts[bc * C_ + i];

    const float4* qsum4 = (const float4*)(sums + (size_t)b * C_ * D_);
    const float4* ksum4 = (const float4*)(sums + ((size_t)B_ + b) * C_ * D_);
    const float4* vsum4 = (const float4*)(sums + ((size_t)2 * B_ + b) * C_ * D_);

    for (int i = tid; i < C_ * 16; i += 256) {
        int c = i >> 4, d4 = i & 15;
        kc4[c * 17 + d4] = ksum4[i];
        vc4[c * 17 + d4] = vsum4[i];
    }
    __syncthreads();

    const int* si = sidx + bc * N_;
    float4* ob = (float4*)(out + (size_t)b * N_ * D_);

    int wave = __builtin_amdgcn_readfirstlane(tid >> 6);
    int lane = tid & 63;

    for (int tt = wave; tt * 2 < qcnt; tt += 4) {
        int t2 = tt * 2;
        // per-tile Q row pointers (wave-uniform; clamped for the tail)
        const float4* qp0 = qsum4 + (size_t)(q0 + min(t2 + 0, qcnt - 1)) * 16;
        const float4* qp1 = qsum4 + (size_t)(q0 + min(t2 + 1, qcnt - 1)) * 16;
        // ---- QK: 2 q-rows x (k=lane, k=lane+64, k=128)
        float s0[2] = {0, 0}, s1[2] = {0, 0}, s2[2] = {0, 0};
#pragma unroll 4
        for (int d4 = 0; d4 < 16; d4++) {
            float4 kv0 = kc4[lane * 17 + d4];
            float4 kv1 = kc4[(lane + 64) * 17 + d4];
            float4 kv2 = kc4[128 * 17 + d4];
            float4 qv0 = qp0[d4], qv1 = qp1[d4];
            s0[0] += qv0.x * kv0.x + qv0.y * kv0.y + qv0.z * kv0.z + qv0.w * kv0.w;
            s1[0] += qv0.x * kv1.x + qv0.y * kv1.y + qv0.z * kv1.z + qv0.w * kv1.w;
            s2[0] += qv0.x * kv2.x + qv0.y * kv2.y + qv0.z * kv2.z + qv0.w * kv2.w;
            s0[1] += qv1.x * kv0.x + qv1.y * kv0.y + qv1.z * kv0.z + qv1.w * kv0.w;
            s1[1] += qv1.x * kv1.x + qv1.y * kv1.y + qv1.z * kv1.z + qv1.w * kv1.w;
            s2[1] += qv1.x * kv2.x + qv1.y * kv2.y + qv1.z * kv2.z + qv1.w * kv2.w;
        }
        // ---- softmax (weighted by counts, renormalized)
#pragma unroll
        for (int r = 0; r < 2; r++) {
            if (t2 + r >= qcnt) break;
            int qrow = q0 + t2 + r;
            float m = fmaxf(s0[r], s1[r]);
            if (lane == 0) m = fmaxf(m, s2[r]);
            for (int off = 32; off > 0; off >>= 1)
                m = fmaxf(m, __shfl_xor(m, off, 64));
            float e0 = __expf(s0[r] - m) * cnt_s[lane];
            float e1 = __expf(s1[r] - m) * cnt_s[lane + 64];
            float e2 = (lane == 0) ? __expf(s2[r] - m) * cnt_s[128] : 0.f;
            float sum = e0 + e1 + e2;
            for (int off = 32; off > 0; off >>= 1)
                sum += __shfl_xor(sum, off, 64);
            float inv = 1.f / sum;
            float a0 = e0 * inv, a1 = e1 * inv;
            arow[wave][r][lane] = a0;
            arow[wave][r][64 + lane] = a1;
            if (lane == 0) {
                arow[wave][r][128] = e2 * inv;
                aout[b * C_ + qrow] = a0;   // A_full[:, :, 0]
            }
        }
        __builtin_amdgcn_s_waitcnt(0);       // arow writes visible in-wave
        __builtin_amdgcn_sched_barrier(0);   // don't let ds_reads hoist above
        // ---- V product: rr=row (lane>>5), half=k-range half, d4=lane&15
        int rr = lane >> 5;
        int half = (lane >> 4) & 1;
        int d4 = lane & 15;
        const float4* ar4 = (const float4*)arow[wave][rr];
        float4 o = make_float4(0.f, 0.f, 0.f, 0.f);
        int k4base = half * 16;
        for (int k4 = k4base; k4 < k4base + 16; k4++) {
            float4 a4 = ar4[k4];
            float4 v0 = vc4[(k4 * 4 + 0) * 17 + d4];
            float4 v1 = vc4[(k4 * 4 + 1) * 17 + d4];
            float4 v2 = vc4[(k4 * 4 + 2) * 17 + d4];
            float4 v3 = vc4[(k4 * 4 + 3) * 17 + d4];
            o.x += a4.x * v0.x + a4.y * v1.x + a4.z * v2.x + a4.w * v3.x;
            o.y += a4.x * v0.y + a4.y * v1.y + a4.z * v2.y + a4.w * v3.y;
            o.z += a4.x * v0.z + a4.y * v1.z + a4.z * v2.z + a4.w * v3.z;
            o.w += a4.x * v0.w + a4.y * v1.w + a4.z * v2.w + a4.w * v3.w;
        }
        // combine the two k-halves (lanes l and l^16 hold partials of same row)
        o.x += __shfl_xor(o.x, 16, 64);
        o.y += __shfl_xor(o.y, 16, 64);
        o.z += __shfl_xor(o.z, 16, 64);
        o.w += __shfl_xor(o.w, 16, 64);
        {   // k=128 tail (identical in both halves; added AFTER the combine)
            float a128 = arow[wave][rr][128];
            float4 vv = vc4[128 * 17 + d4];
            o.x += a128 * vv.x; o.y += a128 * vv.y;
            o.z += a128 * vv.z; o.w += a128 * vv.w;
        }
        // ---- direct scatter: member list split between the two halves
        if (t2 + rr < qcnt) {
            int qrow = q0 + t2 + rr;
            int s = offsets[bc * (C_ + 1) + qrow];
            int e = offsets[bc * (C_ + 1) + qrow + 1];
            for (int mm = s + half; mm < e; mm += 2) {
                int n = si[mm];              // broadcast load (same addr, 16 lanes)
                ob[n * 16 + d4] = o;         // 16 lanes -> contiguous 256B row
            }
        }
    }
}

// ---------------------------------------------------------------- launch
extern "C" void kernel_launch(void* const* d_in, const int* in_sizes, int n_in,
                              void* d_out, int out_size, void* d_ws, size_t ws_size,
                              hipStream_t stream) {
    const float* q = (const float*)d_in[0];
    const float* k = (const float*)d_in[1];
    const float* v = (const float*)d_in[2];
    const int* cl = (const int*)d_in[3];
    float* out = (float*)d_out;
    float* aout = out + (size_t)B_ * N_ * D_;   // A_full[:, :, 0] tail

    float* ws = (float*)d_ws;
    float* counts = ws;                                   // [4][C_] (pad to 1024)
    float* sums = ws + 1024;                              // [3][B_][C_][D_] pre-scaled centers
    int* offsets = (int*)(sums + (size_t)3 * B_ * C_ * D_); // [4][C_+1]
    int* sidx = offsets + 4 * (C_ + 1);                   // [4][N_]

    k_sort<<<BC_, 1024, 0, stream>>>(cl, counts, offsets, sidx);
    k_segsum4<<<B_ * CG_, 256, 0, stream>>>(q, k, v, offsets, sidx, sums);
    k_attn_sc<<<17 * B_, 256, 0, stream>>>(sums, counts, offsets, sidx, out, aout);
}